// Round 1
// baseline (33.424 us; speedup 1.0000x reference)
//
#include <hip/hip_runtime.h>

// TimeDependentRatchetPolicyRIM: elementwise policy map, memory-bound.
// B rows; out is (B, 17) f32: [u_star[0..15]*dw_share, C].
// Strategy: 1 thread = 1 row for compute; stage dw/C in LDS; block writes
// its contiguous 256*17-float output slab with coalesced float4 stores.

#define NCOL 17
#define BLK 256
#define SLAB (BLK * NCOL)          // 4352 floats per block
#define SLAB4 (SLAB / 4)           // 1088 float4 per block

__global__ __launch_bounds__(BLK) void ratchet_kernel(
    const float* __restrict__ X,       // (B,2) wealth, habit
    const float* __restrict__ TmT,     // (B,)
    const float* __restrict__ y,       // (B,)
    const float* __restrict__ u_star,  // (16,)
    const float* __restrict__ s_grid,  // (2048,) linspace(0,1)
    const float* __restrict__ z_tilde, // (2048,)
    float* __restrict__ out,           // (B,17)
    long long B)
{
    __shared__ float s_dw[BLK];
    __shared__ float s_C[BLK];
    __shared__ float s_u[16];

    const int tid = threadIdx.x;
    const long long row = (long long)blockIdx.x * BLK + tid;
    const long long rowc = row < B ? row : (B - 1);

    if (tid < 16) s_u[tid] = u_star[tid];

    // ---- phase 1: per-row policy compute ----
    const float2 xh = ((const float2*)X)[rowc];
    const float wealth = xh.x;
    const float habit  = xh.y;
    const float tau    = TmT[rowc];
    const float yv     = y[rowc];

    // z_tau = interp(clip(tau,0,1), s_grid, z_tilde); uniform grid + refine
    float s = fminf(fmaxf(tau, 0.0f), 1.0f);
    int idx = (int)(s * 2047.0f);
    idx = idx < 2046 ? idx : 2046;
    idx = idx > 0 ? idx : 0;
    float g0 = s_grid[idx];
    float g1 = s_grid[idx + 1];
    if (s < g0 && idx > 0) {
        --idx; g1 = g0; g0 = s_grid[idx];
    } else if (s >= g1 && idx < 2046) {
        ++idx; g0 = g1; g1 = s_grid[idx + 1];
    }
    const float z0 = z_tilde[idx];
    const float z1 = z_tilde[idx + 1];
    const float frac = (s - g0) / (g1 - g0);
    const float z = z0 + (z1 - z0) * frac;

    const float y_eff = fmaxf(yv, 1e-12f);
    const float ratio = fmaxf(z / y_eff, 1e-24f);
    const float c_b   = cbrtf(ratio);            // GAMMA = 3
    const float h3    = habit * habit * habit;
    // ALPHA_RAISE = 1 -> c_raised = c_on_boundary
    const float C     = (y_eff * h3 <= z) ? fmaxf(c_b, habit) : habit;
    const float ann   = (1.0f - expf(-0.02f * tau)) * 50.0f;  // (1-e^{-R tau})/R
    const float pvC   = ann * C;
    float dw = (wealth - pvC) / fmaxf(wealth, 1e-12f);
    dw = fminf(fmaxf(dw, 0.0f), 1.0f);           // DW_FLOOR = 0

    s_dw[tid] = dw;
    s_C[tid]  = C;
    __syncthreads();

    // ---- phase 2: coalesced float4 writes of the block's output slab ----
    const long long slab_base = (long long)blockIdx.x * SLAB;   // in floats
    float4* out4 = (float4*)(out + slab_base);
    const long long total = B * NCOL;

    for (int m = tid; m < SLAB4; m += BLK) {
        const int e = 4 * m;
        if (slab_base + e + 3 >= total && slab_base + e >= total) break;
        float v[4];
        #pragma unroll
        for (int j = 0; j < 4; ++j) {
            const unsigned ee = (unsigned)(e + j);
            const unsigned r  = ee / 17u;
            const unsigned c  = ee - r * 17u;
            v[j] = (c < 16u) ? s_u[c] * s_dw[r] : s_C[r];
        }
        out4[m] = make_float4(v[0], v[1], v[2], v[3]);
    }
}

extern "C" void kernel_launch(void* const* d_in, const int* in_sizes, int n_in,
                              void* d_out, int out_size, void* d_ws, size_t ws_size,
                              hipStream_t stream) {
    const float* X       = (const float*)d_in[0];
    const float* TmT     = (const float*)d_in[1];
    const float* y       = (const float*)d_in[2];
    const float* u_star  = (const float*)d_in[3];
    const float* s_grid  = (const float*)d_in[4];
    const float* z_tilde = (const float*)d_in[5];
    float* out = (float*)d_out;

    const long long B = in_sizes[1];  // TmT is (B,)
    const int blocks = (int)((B + BLK - 1) / BLK);
    ratchet_kernel<<<blocks, BLK, 0, stream>>>(X, TmT, y, u_star, s_grid,
                                               z_tilde, out, B);
}